// Round 3
// baseline (789.329 us; speedup 1.0000x reference)
//
#include <hip/hip_runtime.h>

// SelfAttention (SAGAN-style), MI355X gfx950.
// proj (f16 MFMA GEMM) -> flash attn (32x32x16 swapped-operand, in-reg P,
// O^T accumulator, j-split x2) -> combine (normalize, no transpose).
//
// ws layout (~64.5 MB):
//   qw  f16 [4][4096][256]    8 MB  (Q rows)
//   kw  f16 [4][4096][256]    8 MB  (K rows)
//   vw  f16 [4][512][4096]   16 MB  (V, c-major)
//   op  f16 [2][4][512][4096] 32 MB (unnormalized O^T partials, c-major)
//   st  f32 [2][4][4096][2]  0.5 MB (m, l per row per j-half)

#define NPIX 4096
#define CIN  512

typedef _Float16 f16x4 __attribute__((ext_vector_type(4)));
typedef _Float16 f16x8 __attribute__((ext_vector_type(8)));
typedef float    f32x4 __attribute__((ext_vector_type(4)));
typedef float    f32x16 __attribute__((ext_vector_type(16)));

#define MFMA16(a, b, c) __builtin_amdgcn_mfma_f32_16x16x16f16(a, b, c, 0, 0, 0)
#define MFMA32(a, b, c) __builtin_amdgcn_mfma_f32_32x32x16_f16(a, b, c, 0, 0, 0)

__device__ __forceinline__ void gld_lds16(const void* g, void* l) {
    __builtin_amdgcn_global_load_lds(
        (const __attribute__((address_space(1))) unsigned int*)g,
        (__attribute__((address_space(3))) unsigned int*)l, 16, 0, 0);
}

// ---------------------------------------------------------------------------
// Projection (unchanged from R2): out[o][n], o<256->Q, <512->K, else->V.
// ---------------------------------------------------------------------------
__global__ __launch_bounds__(256) void proj_kernel(
    const float* __restrict__ x,
    const float* __restrict__ f_w, const float* __restrict__ f_b,
    const float* __restrict__ g_w, const float* __restrict__ g_b,
    const float* __restrict__ h_w, const float* __restrict__ h_b,
    _Float16* __restrict__ qw, _Float16* __restrict__ kw,
    _Float16* __restrict__ vw)
{
    const int b  = blockIdx.z;
    const int n0 = blockIdx.x * 64;
    const int o0 = blockIdx.y * 64;

    const float* wsrc; const float* bsrc;
    if (o0 < 256)      { wsrc = f_w + (size_t)o0 * CIN;         bsrc = f_b + o0; }
    else if (o0 < 512) { wsrc = g_w + (size_t)(o0 - 256) * CIN; bsrc = g_b + (o0 - 256); }
    else               { wsrc = h_w + (size_t)(o0 - 512) * CIN; bsrc = h_b + (o0 - 512); }

    __shared__ _Float16 Wt[64][40];
    __shared__ _Float16 Xt[64][40];

    const int t = threadIdx.x;
    const int lane = t & 63, wv = t >> 6;
    const int wm = wv >> 1, wn = wv & 1;
    const int gi = lane >> 4, li = lane & 15;

    f32x4 acc[2][2];
    #pragma unroll
    for (int i = 0; i < 2; ++i)
        #pragma unroll
        for (int j = 0; j < 2; ++j) acc[i][j] = f32x4{0.f, 0.f, 0.f, 0.f};

    for (int kk = 0; kk < CIN; kk += 32) {
        {
            const int r = t >> 2, c8 = (t & 3) * 8;
            const float* p = wsrc + (size_t)r * CIN + kk + c8;
            const float4 v0 = *(const float4*)p;
            const float4 v1 = *(const float4*)(p + 4);
            _Float16* d = &Wt[r][c8];
            d[0] = (_Float16)v0.x; d[1] = (_Float16)v0.y;
            d[2] = (_Float16)v0.z; d[3] = (_Float16)v0.w;
            d[4] = (_Float16)v1.x; d[5] = (_Float16)v1.y;
            d[6] = (_Float16)v1.z; d[7] = (_Float16)v1.w;
        }
        {
            const int c = t >> 3, n8 = (t & 7) * 8;
            const float* p = x + ((size_t)b * CIN + kk + c) * NPIX + n0 + n8;
            const float4 v0 = *(const float4*)p;
            const float4 v1 = *(const float4*)(p + 4);
            Xt[n8 + 0][c] = (_Float16)v0.x; Xt[n8 + 1][c] = (_Float16)v0.y;
            Xt[n8 + 2][c] = (_Float16)v0.z; Xt[n8 + 3][c] = (_Float16)v0.w;
            Xt[n8 + 4][c] = (_Float16)v1.x; Xt[n8 + 5][c] = (_Float16)v1.y;
            Xt[n8 + 6][c] = (_Float16)v1.z; Xt[n8 + 7][c] = (_Float16)v1.w;
        }
        __syncthreads();
        #pragma unroll
        for (int kh = 0; kh < 2; ++kh) {
            const int ko = kh * 16 + gi * 4;
            f16x4 a0 = *(const f16x4*)&Wt[wm * 32 +      li][ko];
            f16x4 a1 = *(const f16x4*)&Wt[wm * 32 + 16 + li][ko];
            f16x4 b0 = *(const f16x4*)&Xt[wn * 32 +      li][ko];
            f16x4 b1 = *(const f16x4*)&Xt[wn * 32 + 16 + li][ko];
            acc[0][0] = MFMA16(a0, b0, acc[0][0]);
            acc[0][1] = MFMA16(a0, b1, acc[0][1]);
            acc[1][0] = MFMA16(a1, b0, acc[1][0]);
            acc[1][1] = MFMA16(a1, b1, acc[1][1]);
        }
        __syncthreads();
    }

    #pragma unroll
    for (int mf = 0; mf < 2; ++mf)
        #pragma unroll
        for (int nf = 0; nf < 2; ++nf) {
            const int obase = o0 + wm * 32 + mf * 16 + gi * 4;
            const int n     = n0 + wn * 32 + nf * 16 + li;
            const int brel  = wm * 32 + mf * 16 + gi * 4;
            float v[4];
            #pragma unroll
            for (int r = 0; r < 4; ++r) v[r] = acc[mf][nf][r] + bsrc[brel + r];
            if (o0 < 512) {
                _Float16* dst = (o0 < 256) ? qw : kw;
                const int kb  = (o0 < 256) ? obase : (obase - 256);
                f16x4 pk;
                pk[0] = (_Float16)v[0]; pk[1] = (_Float16)v[1];
                pk[2] = (_Float16)v[2]; pk[3] = (_Float16)v[3];
                *(f16x4*)&dst[((size_t)b * NPIX + n) * 256 + kb] = pk;
            } else {
                #pragma unroll
                for (int r = 0; r < 4; ++r)
                    vw[((size_t)b * CIN + (obase - 512 + r)) * NPIX + n] =
                        (_Float16)v[r];
            }
        }
}

// ---------------------------------------------------------------------------
// Flash attention, one j-half (2048 keys). 4 waves x 32 Q-rows, BN=32.
// Swapped QK^T (S^T = K x Q) -> in-register online softmax -> PV with
// acc-order-matched V reads -> O^T[c][i] partials.
// LDS: double-buffered K (16KB) + V (32KB), XOR-swizzled, gld_lds-staged.
// ---------------------------------------------------------------------------
__global__ __launch_bounds__(256) void attn_kernel(
    const _Float16* __restrict__ qw, const _Float16* __restrict__ kw,
    const _Float16* __restrict__ vw,
    _Float16* __restrict__ opart, float* __restrict__ stats)
{
    const int b = blockIdx.z, jh = blockIdx.y, rb = blockIdx.x;
    const int t = threadIdx.x, l = t & 63, wv = t >> 6;
    const int li = l & 31, g = l >> 5;
    const int i_row = rb * 128 + wv * 32 + li;

    // K rows: 512B, swizzle byte ^= (row&7)<<4. V rows: 64B, swizzle (row&3)<<4.
    __shared__ _Float16 Kt[2][32 * 256];   // 16 KB each
    __shared__ _Float16 Vt[2][512 * 32];   // 32 KB each

    // Q fragments: qf[ks][e] = Q[i_row][ks*16 + 8g + e]
    f16x8 qf[16];
    {
        const _Float16* qb = qw + ((size_t)b * NPIX + i_row) * 256 + 8 * g;
        #pragma unroll
        for (int ks = 0; ks < 16; ++ks) qf[ks] = *(const f16x8*)(qb + ks * 16);
    }

    f32x16 oacc[16];
    #pragma unroll
    for (int i = 0; i < 16; ++i)
        #pragma unroll
        for (int e = 0; e < 16; ++e) oacc[i][e] = 0.f;
    float m_run = -__builtin_inff();
    float l_run = 0.f;

    auto stage = [&](int buf, int j0) {
        // K tile: 32 rows x 512B, linear LDS dest, inverse-swizzled source
        #pragma unroll
        for (int q = 0; q < 4; ++q) {
            const int row  = q * 8 + (t >> 5);
            const int colb = (t & 31) * 16;
            const char* src =
                (const char*)(kw + ((size_t)b * NPIX + j0 + row) * 256) +
                (colb ^ ((row & 7) << 4));
            char* dst = (char*)Kt[buf] + q * 4096 + t * 16;
            gld_lds16(src, dst);
        }
        // V tile: 512 rows x 64B
        #pragma unroll
        for (int q = 0; q < 8; ++q) {
            const int row  = q * 64 + (t >> 2);
            const int colb = (t & 3) * 16;
            const char* src =
                (const char*)(vw + ((size_t)b * CIN + row) * NPIX + j0) +
                (colb ^ ((row & 3) << 4));
            char* dst = (char*)Vt[buf] + q * 4096 + t * 16;
            gld_lds16(src, dst);
        }
    };

    stage(0, jh * 2048);
    __syncthreads();

    for (int it = 0; it < 64; ++it) {
        const int cur = it & 1;
        if (it < 63) stage(cur ^ 1, jh * 2048 + (it + 1) * 32);

        const char* kb = (const char*)Kt[cur];
        const char* vb = (const char*)Vt[cur];

        // QK^T: S^T[j][i]; A = K (row j = li), B = Q (col i = li).
        f32x16 s;
        #pragma unroll
        for (int e = 0; e < 16; ++e) s[e] = 0.f;
        {
            const char* kr = kb + li * 512;
            const int sw = (li & 7) << 4;
            #pragma unroll
            for (int ks = 0; ks < 16; ++ks) {
                f16x8 kf = *(const f16x8*)(kr + ((ks * 32 + 16 * g) ^ sw));
                s = MFMA32(kf, qf[ks], s);
            }
        }

        // online softmax: lane covers row i = li (g-halves duplicate after shfl)
        float tmax = s[0];
        #pragma unroll
        for (int e = 1; e < 16; ++e) tmax = fmaxf(tmax, s[e]);
        tmax = fmaxf(tmax, __shfl_xor(tmax, 32));
        const float mnew = fmaxf(m_run, tmax);
        const float sc = __expf(m_run - mnew);   // first iter: exp(-inf)=0
        float p[16];
        float rs = 0.f;
        #pragma unroll
        for (int e = 0; e < 16; ++e) { p[e] = __expf(s[e] - mnew); rs += p[e]; }
        rs += __shfl_xor(rs, 32);
        l_run = l_run * sc + rs;
        m_run = mnew;

        if (__any((int)(sc < 1.f))) {
            #pragma unroll
            for (int ct = 0; ct < 16; ++ct)
                #pragma unroll
                for (int e = 0; e < 16; ++e) oacc[ct][e] *= sc;
        }

        // P -> f16 fragments (acc reg order r = e + 8*ks2, j = (r&3)+8*(r>>2)+4g)
        f16x8 pa0, pa1;
        #pragma unroll
        for (int e = 0; e < 8; ++e) {
            pa0[e] = (_Float16)p[e];
            pa1[e] = (_Float16)p[8 + e];
        }

        // PV: O^T[c][i] += V[c][j] * P^T[j][i]; A-slot j-order matches acc order:
        // slot e<4 -> j = ks2*16 + 4g + e ; e>=4 -> j = ks2*16 + 8 + 4g + (e-4)
        #pragma unroll
        for (int ct = 0; ct < 16; ++ct) {
            const int c = ct * 32 + li;
            const char* vr = vb + c * 64;
            const int sw = (c & 3) << 4;
            f16x8 va;
            *(f16x4*)&va         = *(const f16x4*)(vr + ((8 * g) ^ sw));
            *((f16x4*)&va + 1)   = *(const f16x4*)(vr + ((16 + 8 * g) ^ sw));
            oacc[ct] = MFMA32(va, pa0, oacc[ct]);
            f16x8 vc;
            *(f16x4*)&vc         = *(const f16x4*)(vr + ((32 + 8 * g) ^ sw));
            *((f16x4*)&vc + 1)   = *(const f16x4*)(vr + ((48 + 8 * g) ^ sw));
            oacc[ct] = MFMA32(vc, pa1, oacc[ct]);
        }
        __syncthreads();
    }

    // epilogue: O^T partial (c-major) + stats
    const size_t ob = (size_t)(jh * 4 + b) * 512 * NPIX;
    #pragma unroll
    for (int ct = 0; ct < 16; ++ct)
        #pragma unroll
        for (int r = 0; r < 16; ++r) {
            const int c = ct * 32 + (r & 3) + 8 * (r >> 2) + 4 * g;
            opart[ob + (size_t)c * NPIX + i_row] = (_Float16)oacc[ct][r];
        }
    if (g == 0) {
        const size_t idx = ((size_t)(jh * 4 + b) * NPIX + i_row) * 2;
        stats[idx]     = m_run;
        stats[idx + 1] = l_run;
    }
}

// ---------------------------------------------------------------------------
// Combine j-half partials (both c-major): no transpose needed.
// ---------------------------------------------------------------------------
__global__ __launch_bounds__(256) void combine_kernel(
    const _Float16* __restrict__ opart, const float* __restrict__ stats,
    float* __restrict__ out)
{
    const int b  = blockIdx.y;
    const int i0 = blockIdx.x * 64;
    const int t  = threadIdx.x;

    __shared__ float a0s[64], a1s[64];
    if (t < 64) {
        const int i = i0 + t;
        const size_t r0 = ((size_t)b * NPIX + i) * 2;
        const size_t r1 = ((size_t)(4 + b) * NPIX + i) * 2;
        const float m0 = stats[r0], l0 = stats[r0 + 1];
        const float m1 = stats[r1], l1 = stats[r1 + 1];
        const float M  = fmaxf(m0, m1);
        const float w0 = __expf(m0 - M), w1 = __expf(m1 - M);
        const float inv = 1.0f / (l0 * w0 + l1 * w1);
        a0s[t] = w0 * inv;
        a1s[t] = w1 * inv;
    }
    __syncthreads();

    const int ci = t >> 3;          // 32 c-rows per pass
    const int ii = (t & 7) * 8;     // 8-wide i chunk
    #pragma unroll 4
    for (int pp = 0; pp < 16; ++pp) {
        const int c = pp * 32 + ci;
        const _Float16* p0 = opart + ((size_t)b * CIN + c) * NPIX + i0 + ii;
        const _Float16* p1 = opart + ((size_t)(4 + b) * CIN + c) * NPIX + i0 + ii;
        const f16x8 x0 = *(const f16x8*)p0;
        const f16x8 x1 = *(const f16x8*)p1;
        float* dst = out + ((size_t)b * CIN + c) * NPIX + i0 + ii;
        float4 o0, o1;
        o0.x = a0s[ii + 0] * (float)x0[0] + a1s[ii + 0] * (float)x1[0];
        o0.y = a0s[ii + 1] * (float)x0[1] + a1s[ii + 1] * (float)x1[1];
        o0.z = a0s[ii + 2] * (float)x0[2] + a1s[ii + 2] * (float)x1[2];
        o0.w = a0s[ii + 3] * (float)x0[3] + a1s[ii + 3] * (float)x1[3];
        o1.x = a0s[ii + 4] * (float)x0[4] + a1s[ii + 4] * (float)x1[4];
        o1.y = a0s[ii + 5] * (float)x0[5] + a1s[ii + 5] * (float)x1[5];
        o1.z = a0s[ii + 6] * (float)x0[6] + a1s[ii + 6] * (float)x1[6];
        o1.w = a0s[ii + 7] * (float)x0[7] + a1s[ii + 7] * (float)x1[7];
        *(float4*)dst       = o0;
        *(float4*)(dst + 4) = o1;
    }
}

// ---------------------------------------------------------------------------
extern "C" void kernel_launch(void* const* d_in, const int* in_sizes, int n_in,
                              void* d_out, int out_size, void* d_ws,
                              size_t ws_size, hipStream_t stream)
{
    const float* x   = (const float*)d_in[0];
    const float* f_w = (const float*)d_in[1];
    const float* f_b = (const float*)d_in[2];
    const float* g_w = (const float*)d_in[3];
    const float* g_b = (const float*)d_in[4];
    const float* h_w = (const float*)d_in[5];
    const float* h_b = (const float*)d_in[6];
    float* out = (float*)d_out;

    _Float16* qw = (_Float16*)d_ws;
    _Float16* kw = qw + (size_t)4 * NPIX * 256;
    _Float16* vw = kw + (size_t)4 * NPIX * 256;
    _Float16* op = vw + (size_t)4 * CIN * NPIX;
    float* stats = (float*)(op + (size_t)2 * 4 * CIN * NPIX);

    proj_kernel<<<dim3(64, 16, 4), 256, 0, stream>>>(
        x, f_w, f_b, g_w, g_b, h_w, h_b, qw, kw, vw);
    attn_kernel<<<dim3(32, 2, 4), 256, 0, stream>>>(qw, kw, vw, op, stats);
    combine_kernel<<<dim3(64, 4), 256, 0, stream>>>(op, stats, out);
}

// Round 4
// 286.626 us; speedup vs baseline: 2.7539x; 2.7539x over previous
//
#include <hip/hip_runtime.h>

// SelfAttention (SAGAN-style), MI355X gfx950.
// proj (f16 MFMA GEMM) -> flash attn (32x32x16 swapped-operand, in-reg P,
// O^T accumulator, c-split across waves, j-split x2) -> combine.
//
// ws layout (~64.5 MB):
//   qw  f16 [4][4096][256]    8 MB  (Q rows)
//   kw  f16 [4][4096][256]    8 MB  (K rows)
//   vw  f16 [4][512][4096]   16 MB  (V, c-major)
//   op  f16 [2][4][512][4096] 32 MB (unnormalized O^T partials, c-major)
//   st  f32 [2][4][4096][2]  0.5 MB (m, l per row per j-half)

#define NPIX 4096
#define CIN  512

typedef _Float16 f16x4 __attribute__((ext_vector_type(4)));
typedef _Float16 f16x8 __attribute__((ext_vector_type(8)));
typedef float    f32x4 __attribute__((ext_vector_type(4)));
typedef float    f32x16 __attribute__((ext_vector_type(16)));

#define MFMA16(a, b, c) __builtin_amdgcn_mfma_f32_16x16x16f16(a, b, c, 0, 0, 0)
#define MFMA32(a, b, c) __builtin_amdgcn_mfma_f32_32x32x16_f16(a, b, c, 0, 0, 0)

__device__ __forceinline__ void gld_lds16(const void* g, void* l) {
    __builtin_amdgcn_global_load_lds(
        (const __attribute__((address_space(1))) unsigned int*)g,
        (__attribute__((address_space(3))) unsigned int*)l, 16, 0, 0);
}

// ---------------------------------------------------------------------------
// Projection: out[o][n], o<256->Q, <512->K, else->V. (unchanged, works)
// ---------------------------------------------------------------------------
__global__ __launch_bounds__(256) void proj_kernel(
    const float* __restrict__ x,
    const float* __restrict__ f_w, const float* __restrict__ f_b,
    const float* __restrict__ g_w, const float* __restrict__ g_b,
    const float* __restrict__ h_w, const float* __restrict__ h_b,
    _Float16* __restrict__ qw, _Float16* __restrict__ kw,
    _Float16* __restrict__ vw)
{
    const int b  = blockIdx.z;
    const int n0 = blockIdx.x * 64;
    const int o0 = blockIdx.y * 64;

    const float* wsrc; const float* bsrc;
    if (o0 < 256)      { wsrc = f_w + (size_t)o0 * CIN;         bsrc = f_b + o0; }
    else if (o0 < 512) { wsrc = g_w + (size_t)(o0 - 256) * CIN; bsrc = g_b + (o0 - 256); }
    else               { wsrc = h_w + (size_t)(o0 - 512) * CIN; bsrc = h_b + (o0 - 512); }

    __shared__ _Float16 Wt[64][40];
    __shared__ _Float16 Xt[64][40];

    const int t = threadIdx.x;
    const int lane = t & 63, wv = t >> 6;
    const int wm = wv >> 1, wn = wv & 1;
    const int gi = lane >> 4, li = lane & 15;

    f32x4 acc[2][2];
    #pragma unroll
    for (int i = 0; i < 2; ++i)
        #pragma unroll
        for (int j = 0; j < 2; ++j) acc[i][j] = f32x4{0.f, 0.f, 0.f, 0.f};

    for (int kk = 0; kk < CIN; kk += 32) {
        {
            const int r = t >> 2, c8 = (t & 3) * 8;
            const float* p = wsrc + (size_t)r * CIN + kk + c8;
            const float4 v0 = *(const float4*)p;
            const float4 v1 = *(const float4*)(p + 4);
            _Float16* d = &Wt[r][c8];
            d[0] = (_Float16)v0.x; d[1] = (_Float16)v0.y;
            d[2] = (_Float16)v0.z; d[3] = (_Float16)v0.w;
            d[4] = (_Float16)v1.x; d[5] = (_Float16)v1.y;
            d[6] = (_Float16)v1.z; d[7] = (_Float16)v1.w;
        }
        {
            const int c = t >> 3, n8 = (t & 7) * 8;
            const float* p = x + ((size_t)b * CIN + kk + c) * NPIX + n0 + n8;
            const float4 v0 = *(const float4*)p;
            const float4 v1 = *(const float4*)(p + 4);
            Xt[n8 + 0][c] = (_Float16)v0.x; Xt[n8 + 1][c] = (_Float16)v0.y;
            Xt[n8 + 2][c] = (_Float16)v0.z; Xt[n8 + 3][c] = (_Float16)v0.w;
            Xt[n8 + 4][c] = (_Float16)v1.x; Xt[n8 + 5][c] = (_Float16)v1.y;
            Xt[n8 + 6][c] = (_Float16)v1.z; Xt[n8 + 7][c] = (_Float16)v1.w;
        }
        __syncthreads();
        #pragma unroll
        for (int kh = 0; kh < 2; ++kh) {
            const int ko = kh * 16 + gi * 4;
            f16x4 a0 = *(const f16x4*)&Wt[wm * 32 +      li][ko];
            f16x4 a1 = *(const f16x4*)&Wt[wm * 32 + 16 + li][ko];
            f16x4 b0 = *(const f16x4*)&Xt[wn * 32 +      li][ko];
            f16x4 b1 = *(const f16x4*)&Xt[wn * 32 + 16 + li][ko];
            acc[0][0] = MFMA16(a0, b0, acc[0][0]);
            acc[0][1] = MFMA16(a0, b1, acc[0][1]);
            acc[1][0] = MFMA16(a1, b0, acc[1][0]);
            acc[1][1] = MFMA16(a1, b1, acc[1][1]);
        }
        __syncthreads();
    }

    #pragma unroll
    for (int mf = 0; mf < 2; ++mf)
        #pragma unroll
        for (int nf = 0; nf < 2; ++nf) {
            const int obase = o0 + wm * 32 + mf * 16 + gi * 4;
            const int n     = n0 + wn * 32 + nf * 16 + li;
            const int brel  = wm * 32 + mf * 16 + gi * 4;
            float v[4];
            #pragma unroll
            for (int r = 0; r < 4; ++r) v[r] = acc[mf][nf][r] + bsrc[brel + r];
            if (o0 < 512) {
                _Float16* dst = (o0 < 256) ? qw : kw;
                const int kb  = (o0 < 256) ? obase : (obase - 256);
                f16x4 pk;
                pk[0] = (_Float16)v[0]; pk[1] = (_Float16)v[1];
                pk[2] = (_Float16)v[2]; pk[3] = (_Float16)v[3];
                *(f16x4*)&dst[((size_t)b * NPIX + n) * 256 + kb] = pk;
            } else {
                #pragma unroll
                for (int r = 0; r < 4; ++r)
                    vw[((size_t)b * CIN + (obase - 512 + r)) * NPIX + n] =
                        (_Float16)v[r];
            }
        }
}

// ---------------------------------------------------------------------------
// Flash attention, one j-half (2048 keys). 8 waves = 4 row-groups x 2 c-halves.
// Wave = 32 Q-rows x 256 channels -> oacc 128 f32/lane (no spill).
// K: gld_lds, 32-slot XOR swizzle (conflict-free). V: reg-staged, 72B rows.
// XCD swizzle: bid&7 -> (jh,b): per-XCD K/V working set is L2-resident.
// ---------------------------------------------------------------------------
__global__ __launch_bounds__(512, 2) void attn_kernel(
    const _Float16* __restrict__ qw, const _Float16* __restrict__ kw,
    const _Float16* __restrict__ vw,
    _Float16* __restrict__ opart, float* __restrict__ stats)
{
    const int bid = blockIdx.x;
    const int xcd = bid & 7;
    const int jh = xcd & 1, b = xcd >> 1;
    const int rb = bid >> 3;
    const int t = threadIdx.x, l = t & 63, wv = t >> 6;
    const int li = l & 31, g = l >> 5;
    const int rg = wv >> 1, ch = wv & 1;
    const int i_row = rb * 128 + rg * 32 + li;

    __shared__ char Kt[2][16384];        // 32 rows x 512B, XOR-swizzled
    __shared__ char Vt[2][512 * 72];     // 512 rows x 64B data + 8B pad

    // Q fragments: qf[ks] = Q[i_row][ks*16 + 8g .. +7]
    f16x8 qf[16];
    {
        const _Float16* qb = qw + ((size_t)b * NPIX + i_row) * 256 + 8 * g;
        #pragma unroll
        for (int ks = 0; ks < 16; ++ks) qf[ks] = *(const f16x8*)(qb + ks * 16);
    }

    f32x16 oacc[8];
    #pragma unroll
    for (int i = 0; i < 8; ++i)
        #pragma unroll
        for (int e = 0; e < 16; ++e) oacc[i][e] = 0.f;
    float m_run = -__builtin_inff();
    float l_run = 0.f;

    f16x8 vreg[4];

    auto stageK = [&](int buf, int j0) {
        #pragma unroll
        for (int q = 0; q < 2; ++q) {
            const int slot = q * 512 + t;
            const int row  = slot >> 5;
            const int colb = (slot & 31) * 16;
            const char* src =
                (const char*)(kw + ((size_t)b * NPIX + j0 + row) * 256) +
                (colb ^ ((row & 31) << 4));
            gld_lds16(src, Kt[buf] + slot * 16);
        }
    };
    auto loadV = [&](int j0) {
        #pragma unroll
        for (int q = 0; q < 4; ++q) {
            const int c  = q * 128 + (t >> 2);
            const int jj = (t & 3) * 8;
            vreg[q] = *(const f16x8*)(vw + ((size_t)b * CIN + c) * NPIX + j0 + jj);
        }
    };
    auto writeV = [&](int buf) {
        #pragma unroll
        for (int q = 0; q < 4; ++q) {
            const int c = q * 128 + (t >> 2);
            char* d = Vt[buf] + c * 72 + (t & 3) * 16;
            *(f16x4*)d       = *(f16x4*)&vreg[q];
            *(f16x4*)(d + 8) = *((f16x4*)&vreg[q] + 1);
        }
    };

    const int jbase = jh * 2048;
    stageK(0, jbase);
    loadV(jbase);
    writeV(0);
    __syncthreads();

    for (int it = 0; it < 64; ++it) {
        const int cur = it & 1;
        if (it < 63) {
            stageK(cur ^ 1, jbase + (it + 1) * 32);
            loadV(jbase + (it + 1) * 32);
        }

        // QK^T: S^T[j][i]; A = K row j=li, B = Q col i=li.
        f32x16 s;
        #pragma unroll
        for (int e = 0; e < 16; ++e) s[e] = 0.f;
        {
            const char* kr = Kt[cur] + li * 512;
            const int sw = (li & 31) << 4;
            #pragma unroll
            for (int ks = 0; ks < 16; ++ks) {
                f16x8 kf = *(const f16x8*)(kr + ((ks * 32 + 16 * g) ^ sw));
                s = MFMA32(kf, qf[ks], s);
            }
        }

        // stage next V tile into LDS (buffer not read this iter)
        if (it < 63) writeV(cur ^ 1);

        // online softmax, defer-max (THR=5). Lane owns row i=li (dup over g).
        float tmax = s[0];
        #pragma unroll
        for (int e = 1; e < 16; ++e) tmax = fmaxf(tmax, s[e]);
        tmax = fmaxf(tmax, __shfl_xor(tmax, 32));
        if (!__all((int)(tmax - m_run <= 5.f))) {
            const float mnew = fmaxf(m_run, tmax);
            const float sc = __expf(m_run - mnew);  // first iter: 0
            #pragma unroll
            for (int ct = 0; ct < 8; ++ct)
                #pragma unroll
                for (int e = 0; e < 16; ++e) oacc[ct][e] *= sc;
            l_run *= sc;
            m_run = mnew;
        }
        float p[16];
        float rs = 0.f;
        #pragma unroll
        for (int e = 0; e < 16; ++e) { p[e] = __expf(s[e] - m_run); rs += p[e]; }
        rs += __shfl_xor(rs, 32);
        l_run += rs;

        f16x8 pa0, pa1;
        #pragma unroll
        for (int e = 0; e < 8; ++e) {
            pa0[e] = (_Float16)p[e];
            pa1[e] = (_Float16)p[8 + e];
        }

        // PV: O^T[c][i] += V[c][j] * P^T[j][i]  (slot pairing verified in R3)
        #pragma unroll
        for (int ct = 0; ct < 8; ++ct) {
            const int c = ch * 256 + ct * 32 + li;
            const char* vr = Vt[cur] + c * 72;
            f16x8 va;
            *(f16x4*)&va       = *(const f16x4*)(vr + 8 * g);
            *((f16x4*)&va + 1) = *(const f16x4*)(vr + 16 + 8 * g);
            oacc[ct] = MFMA32(va, pa0, oacc[ct]);
            f16x8 vc;
            *(f16x4*)&vc       = *(const f16x4*)(vr + 32 + 8 * g);
            *((f16x4*)&vc + 1) = *(const f16x4*)(vr + 48 + 8 * g);
            oacc[ct] = MFMA32(vc, pa1, oacc[ct]);
        }
        __syncthreads();
    }

    // epilogue: O^T partial (c-major) + stats
    const size_t ob = (size_t)(jh * 4 + b) * CIN * NPIX;
    #pragma unroll
    for (int ct = 0; ct < 8; ++ct)
        #pragma unroll
        for (int r = 0; r < 16; ++r) {
            const int c = ch * 256 + ct * 32 + (r & 3) + 8 * (r >> 2) + 4 * g;
            opart[ob + (size_t)c * NPIX + i_row] = (_Float16)oacc[ct][r];
        }
    if (ch == 0 && g == 0) {
        const size_t idx = ((size_t)(jh * 4 + b) * NPIX + i_row) * 2;
        stats[idx]     = m_run;
        stats[idx + 1] = l_run;
    }
}

// ---------------------------------------------------------------------------
// Combine j-half partials (both c-major): no transpose needed.
// ---------------------------------------------------------------------------
__global__ __launch_bounds__(256) void combine_kernel(
    const _Float16* __restrict__ opart, const float* __restrict__ stats,
    float* __restrict__ out)
{
    const int b  = blockIdx.y;
    const int i0 = blockIdx.x * 64;
    const int t  = threadIdx.x;

    __shared__ float a0s[64], a1s[64];
    if (t < 64) {
        const int i = i0 + t;
        const size_t r0 = ((size_t)b * NPIX + i) * 2;
        const size_t r1 = ((size_t)(4 + b) * NPIX + i) * 2;
        const float m0 = stats[r0], l0 = stats[r0 + 1];
        const float m1 = stats[r1], l1 = stats[r1 + 1];
        const float M  = fmaxf(m0, m1);
        const float w0 = __expf(m0 - M), w1 = __expf(m1 - M);
        const float inv = 1.0f / (l0 * w0 + l1 * w1);
        a0s[t] = w0 * inv;
        a1s[t] = w1 * inv;
    }
    __syncthreads();

    const int ci = t >> 3;
    const int ii = (t & 7) * 8;
    #pragma unroll 4
    for (int pp = 0; pp < 16; ++pp) {
        const int c = pp * 32 + ci;
        const _Float16* p0 = opart + ((size_t)b * CIN + c) * NPIX + i0 + ii;
        const _Float16* p1 = opart + ((size_t)(4 + b) * CIN + c) * NPIX + i0 + ii;
        const f16x8 x0 = *(const f16x8*)p0;
        const f16x8 x1 = *(const f16x8*)p1;
        float* dst = out + ((size_t)b * CIN + c) * NPIX + i0 + ii;
        float4 o0, o1;
        o0.x = a0s[ii + 0] * (float)x0[0] + a1s[ii + 0] * (float)x1[0];
        o0.y = a0s[ii + 1] * (float)x0[1] + a1s[ii + 1] * (float)x1[1];
        o0.z = a0s[ii + 2] * (float)x0[2] + a1s[ii + 2] * (float)x1[2];
        o0.w = a0s[ii + 3] * (float)x0[3] + a1s[ii + 3] * (float)x1[3];
        o1.x = a0s[ii + 4] * (float)x0[4] + a1s[ii + 4] * (float)x1[4];
        o1.y = a0s[ii + 5] * (float)x0[5] + a1s[ii + 5] * (float)x1[5];
        o1.z = a0s[ii + 6] * (float)x0[6] + a1s[ii + 6] * (float)x1[6];
        o1.w = a0s[ii + 7] * (float)x0[7] + a1s[ii + 7] * (float)x1[7];
        *(float4*)dst       = o0;
        *(float4*)(dst + 4) = o1;
    }
}

// ---------------------------------------------------------------------------
extern "C" void kernel_launch(void* const* d_in, const int* in_sizes, int n_in,
                              void* d_out, int out_size, void* d_ws,
                              size_t ws_size, hipStream_t stream)
{
    const float* x   = (const float*)d_in[0];
    const float* f_w = (const float*)d_in[1];
    const float* f_b = (const float*)d_in[2];
    const float* g_w = (const float*)d_in[3];
    const float* g_b = (const float*)d_in[4];
    const float* h_w = (const float*)d_in[5];
    const float* h_b = (const float*)d_in[6];
    float* out = (float*)d_out;

    _Float16* qw = (_Float16*)d_ws;
    _Float16* kw = qw + (size_t)4 * NPIX * 256;
    _Float16* vw = kw + (size_t)4 * NPIX * 256;
    _Float16* op = vw + (size_t)4 * CIN * NPIX;
    float* stats = (float*)(op + (size_t)2 * 4 * CIN * NPIX);

    proj_kernel<<<dim3(64, 16, 4), 256, 0, stream>>>(
        x, f_w, f_b, g_w, g_b, h_w, h_b, qw, kw, vw);
    attn_kernel<<<dim3(256), 512, 0, stream>>>(qw, kw, vw, op, stats);
    combine_kernel<<<dim3(64, 4), 256, 0, stream>>>(op, stats, out);
}

// Round 5
// 235.845 us; speedup vs baseline: 3.3468x; 1.2153x over previous
//
#include <hip/hip_runtime.h>

// SelfAttention (SAGAN-style), MI355X gfx950.
// proj (f16 MFMA GEMM) -> flash attn (32x32x16 swapped-operand, QK on ch0
// waves only, P shared via LDS, O^T accumulator, j-split x2) -> combine.
//
// ws layout (~64.5 MB):
//   qw  f16 [4][4096][256]    8 MB  (Q rows)
//   kw  f16 [4][4096][256]    8 MB  (K rows)
//   vw  f16 [4][512][4096]   16 MB  (V, c-major)
//   op  f16 [2][4][512][4096] 32 MB (unnormalized O^T partials, c-major)
//   st  f32 [2][4][4096][2]  0.5 MB (m, l per row per j-half)

#define NPIX 4096
#define CIN  512

typedef _Float16 f16x4 __attribute__((ext_vector_type(4)));
typedef _Float16 f16x8 __attribute__((ext_vector_type(8)));
typedef float    f32x4 __attribute__((ext_vector_type(4)));
typedef float    f32x16 __attribute__((ext_vector_type(16)));

#define MFMA16(a, b, c) __builtin_amdgcn_mfma_f32_16x16x16f16(a, b, c, 0, 0, 0)
#define MFMA32(a, b, c) __builtin_amdgcn_mfma_f32_32x32x16_f16(a, b, c, 0, 0, 0)

__device__ __forceinline__ void gld_lds16(const void* g, void* l) {
    __builtin_amdgcn_global_load_lds(
        (const __attribute__((address_space(1))) unsigned int*)g,
        (__attribute__((address_space(3))) unsigned int*)l, 16, 0, 0);
}

// ---------------------------------------------------------------------------
// Projection: out[o][n], o<256->Q, <512->K, else->V.
// Staging vectorized: W via f16x8 build + 1 b128 store; X via 8 coalesced
// dword loads + 1 b128 transposed-column store (was 16 scalar ds_write_u16).
// ---------------------------------------------------------------------------
__global__ __launch_bounds__(256) void proj_kernel(
    const float* __restrict__ x,
    const float* __restrict__ f_w, const float* __restrict__ f_b,
    const float* __restrict__ g_w, const float* __restrict__ g_b,
    const float* __restrict__ h_w, const float* __restrict__ h_b,
    _Float16* __restrict__ qw, _Float16* __restrict__ kw,
    _Float16* __restrict__ vw)
{
    const int b  = blockIdx.z;
    const int n0 = blockIdx.x * 64;
    const int o0 = blockIdx.y * 64;

    const float* wsrc; const float* bsrc;
    if (o0 < 256)      { wsrc = f_w + (size_t)o0 * CIN;         bsrc = f_b + o0; }
    else if (o0 < 512) { wsrc = g_w + (size_t)(o0 - 256) * CIN; bsrc = g_b + (o0 - 256); }
    else               { wsrc = h_w + (size_t)(o0 - 512) * CIN; bsrc = h_b + (o0 - 512); }

    __shared__ _Float16 Wt[64][40];
    __shared__ _Float16 Xt[64][40];

    const int t = threadIdx.x;
    const int lane = t & 63, wv = t >> 6;
    const int wm = wv >> 1, wn = wv & 1;
    const int gi = lane >> 4, li = lane & 15;

    f32x4 acc[2][2];
    #pragma unroll
    for (int i = 0; i < 2; ++i)
        #pragma unroll
        for (int j = 0; j < 2; ++j) acc[i][j] = f32x4{0.f, 0.f, 0.f, 0.f};

    for (int kk = 0; kk < CIN; kk += 32) {
        {   // W tile 64x32: one b128 store per thread
            const int r = t >> 2, c8 = (t & 3) * 8;
            const float* p = wsrc + (size_t)r * CIN + kk + c8;
            const float4 v0 = *(const float4*)p;
            const float4 v1 = *(const float4*)(p + 4);
            f16x8 w8;
            w8[0] = (_Float16)v0.x; w8[1] = (_Float16)v0.y;
            w8[2] = (_Float16)v0.z; w8[3] = (_Float16)v0.w;
            w8[4] = (_Float16)v1.x; w8[5] = (_Float16)v1.y;
            w8[6] = (_Float16)v1.z; w8[7] = (_Float16)v1.w;
            *(f16x8*)&Wt[r][c8] = w8;
        }
        {   // X tile 32c x 64n: 8 coalesced dword loads, 1 b128 store
            const int cb = (t >> 6) * 8;
            const int nl = t & 63;
            f16x8 xv;
            #pragma unroll
            for (int e = 0; e < 8; ++e)
                xv[e] = (_Float16)x[((size_t)b * CIN + kk + cb + e) * NPIX +
                                    n0 + nl];
            *(f16x8*)&Xt[nl][cb] = xv;
        }
        __syncthreads();
        #pragma unroll
        for (int kh = 0; kh < 2; ++kh) {
            const int ko = kh * 16 + gi * 4;
            f16x4 a0 = *(const f16x4*)&Wt[wm * 32 +      li][ko];
            f16x4 a1 = *(const f16x4*)&Wt[wm * 32 + 16 + li][ko];
            f16x4 b0 = *(const f16x4*)&Xt[wn * 32 +      li][ko];
            f16x4 b1 = *(const f16x4*)&Xt[wn * 32 + 16 + li][ko];
            acc[0][0] = MFMA16(a0, b0, acc[0][0]);
            acc[0][1] = MFMA16(a0, b1, acc[0][1]);
            acc[1][0] = MFMA16(a1, b0, acc[1][0]);
            acc[1][1] = MFMA16(a1, b1, acc[1][1]);
        }
        __syncthreads();
    }

    #pragma unroll
    for (int mf = 0; mf < 2; ++mf)
        #pragma unroll
        for (int nf = 0; nf < 2; ++nf) {
            const int obase = o0 + wm * 32 + mf * 16 + gi * 4;
            const int n     = n0 + wn * 32 + nf * 16 + li;
            const int brel  = wm * 32 + mf * 16 + gi * 4;
            float v[4];
            #pragma unroll
            for (int r = 0; r < 4; ++r) v[r] = acc[mf][nf][r] + bsrc[brel + r];
            if (o0 < 512) {
                _Float16* dst = (o0 < 256) ? qw : kw;
                const int kb  = (o0 < 256) ? obase : (obase - 256);
                f16x4 pk;
                pk[0] = (_Float16)v[0]; pk[1] = (_Float16)v[1];
                pk[2] = (_Float16)v[2]; pk[3] = (_Float16)v[3];
                *(f16x4*)&dst[((size_t)b * NPIX + n) * 256 + kb] = pk;
            } else {
                #pragma unroll
                for (int r = 0; r < 4; ++r)
                    vw[((size_t)b * CIN + (obase - 512 + r)) * NPIX + n] =
                        (_Float16)v[r];
            }
        }
}

// ---------------------------------------------------------------------------
// Flash attention, one j-half (2048 keys). 8 waves = 4 row-groups x 2 c-halves
// (ch = wv&1 so SIMD-sequential pairs mix roles). Only ch=0 computes QK +
// softmax; P fragments (pa0|pa1|sc) shared via dbuf LDS (48B/lane stride,
// conflict-free). One barrier/iter: [stage issues | ch0: QK+SM+Pwrite]
// -> barrier -> [all: PV] -> [writeV next tile].
// ---------------------------------------------------------------------------
__global__ __launch_bounds__(512, 2) void attn_kernel(
    const _Float16* __restrict__ qw, const _Float16* __restrict__ kw,
    const _Float16* __restrict__ vw,
    _Float16* __restrict__ opart, float* __restrict__ stats)
{
    const int bid = blockIdx.x;
    const int xcd = bid & 7;
    const int jh = xcd & 1, b = xcd >> 1;
    const int rb = bid >> 3;
    const int t = threadIdx.x, l = t & 63, wv = t >> 6;
    const int li = l & 31, g = l >> 5;
    const int ch = wv & 1, rg = wv >> 1;
    const int i_row = rb * 128 + rg * 32 + li;

    __shared__ char Kt[2][16384];        // 32 rows x 512B, XOR-swizzled
    __shared__ char Vt[2][512 * 72];     // 512 rows x 64B data + 8B pad
    __shared__ char Pt[2][4][64 * 48];   // per lane: pa0(16) pa1(16) sc(4) pad

    // Q fragments (only QK waves need them)
    f16x8 qf[16];
    if (ch == 0) {
        const _Float16* qb = qw + ((size_t)b * NPIX + i_row) * 256 + 8 * g;
        #pragma unroll
        for (int ks = 0; ks < 16; ++ks) qf[ks] = *(const f16x8*)(qb + ks * 16);
    }

    f32x16 oacc[8];
    #pragma unroll
    for (int i = 0; i < 8; ++i)
        #pragma unroll
        for (int e = 0; e < 16; ++e) oacc[i][e] = 0.f;
    float m_run = -__builtin_inff();
    float l_run = 0.f;

    f16x8 vreg[4];

    auto stageK = [&](int buf, int j0) {
        #pragma unroll
        for (int q = 0; q < 2; ++q) {
            const int slot = q * 512 + t;
            const int row  = slot >> 5;
            const int colb = (slot & 31) * 16;
            const char* src =
                (const char*)(kw + ((size_t)b * NPIX + j0 + row) * 256) +
                (colb ^ ((row & 31) << 4));
            gld_lds16(src, Kt[buf] + slot * 16);
        }
    };
    auto loadV = [&](int j0) {
        #pragma unroll
        for (int q = 0; q < 4; ++q) {
            const int c  = q * 128 + (t >> 2);
            const int jj = (t & 3) * 8;
            vreg[q] = *(const f16x8*)(vw + ((size_t)b * CIN + c) * NPIX + j0 + jj);
        }
    };
    auto writeV = [&](int buf) {
        #pragma unroll
        for (int q = 0; q < 4; ++q) {
            const int c = q * 128 + (t >> 2);
            char* d = Vt[buf] + c * 72 + (t & 3) * 16;
            *(f16x4*)d       = *(f16x4*)&vreg[q];
            *(f16x4*)(d + 8) = *((f16x4*)&vreg[q] + 1);
        }
    };

    const int jbase = jh * 2048;
    stageK(0, jbase);
    loadV(jbase);
    writeV(0);
    __syncthreads();

    for (int it = 0; it < 64; ++it) {
        const int cur = it & 1;
        if (it < 63) {
            stageK(cur ^ 1, jbase + (it + 1) * 32);
            loadV(jbase + (it + 1) * 32);
        }

        f16x8 pa0, pa1;
        if (ch == 0) {
            // QK^T: S^T[j][i]; A = K row j=li, B = Q col i=li.
            f32x16 s;
            #pragma unroll
            for (int e = 0; e < 16; ++e) s[e] = 0.f;
            {
                const char* kr = Kt[cur] + li * 512;
                const int sw = li << 4;
                __builtin_amdgcn_s_setprio(1);
                #pragma unroll
                for (int ks = 0; ks < 16; ++ks) {
                    f16x8 kf = *(const f16x8*)(kr + ((ks * 32 + 16 * g) ^ sw));
                    s = MFMA32(kf, qf[ks], s);
                }
                __builtin_amdgcn_s_setprio(0);
            }

            // online softmax with defer-max (THR=5); lane owns row i=li.
            float tmax = s[0];
            #pragma unroll
            for (int e = 1; e < 16; ++e) tmax = fmaxf(tmax, s[e]);
            tmax = fmaxf(tmax, __shfl_xor(tmax, 32));
            float sc_my = 1.0f;
            if (!__all((int)(tmax - m_run <= 5.f))) {
                const float mnew = fmaxf(m_run, tmax);
                sc_my = __expf(m_run - mnew);   // first iter: exp(-inf)=0
                #pragma unroll
                for (int ct = 0; ct < 8; ++ct)
                    #pragma unroll
                    for (int e = 0; e < 16; ++e) oacc[ct][e] *= sc_my;
                l_run *= sc_my;
                m_run = mnew;
            }
            float p[16];
            float rs = 0.f;
            #pragma unroll
            for (int e = 0; e < 16; ++e) { p[e] = __expf(s[e] - m_run); rs += p[e]; }
            rs += __shfl_xor(rs, 32);
            l_run += rs;

            #pragma unroll
            for (int e = 0; e < 8; ++e) {
                pa0[e] = (_Float16)p[e];
                pa1[e] = (_Float16)p[8 + e];
            }
            // publish P + sc for the ch=1 partner wave
            char* pd = Pt[cur][rg] + l * 48;
            *(f16x8*)pd        = pa0;
            *(f16x8*)(pd + 16) = pa1;
            *(float*)(pd + 32) = sc_my;
        }
        __syncthreads();

        if (ch == 1) {
            const char* ps = Pt[cur][rg] + l * 48;
            pa0 = *(const f16x8*)ps;
            pa1 = *(const f16x8*)(ps + 16);
            const float sc = *(const float*)(ps + 32);
            if (!__all((int)(sc == 1.0f))) {
                #pragma unroll
                for (int ct = 0; ct < 8; ++ct)
                    #pragma unroll
                    for (int e = 0; e < 16; ++e) oacc[ct][e] *= sc;
            }
        }

        // PV: O^T[c][i] += V[c][j] * P^T[j][i]  (slot pairing verified R3/R4)
        __builtin_amdgcn_s_setprio(1);
        #pragma unroll
        for (int ct = 0; ct < 8; ++ct) {
            const int c = ch * 256 + ct * 32 + li;
            const char* vr = Vt[cur] + c * 72;
            f16x8 va;
            *(f16x4*)&va       = *(const f16x4*)(vr + 8 * g);
            *((f16x4*)&va + 1) = *(const f16x4*)(vr + 16 + 8 * g);
            oacc[ct] = MFMA32(va, pa0, oacc[ct]);
            f16x8 vc;
            *(f16x4*)&vc       = *(const f16x4*)(vr + 32 + 8 * g);
            *((f16x4*)&vc + 1) = *(const f16x4*)(vr + 48 + 8 * g);
            oacc[ct] = MFMA32(vc, pa1, oacc[ct]);
        }
        __builtin_amdgcn_s_setprio(0);

        // stage next V tile (buffer not read until after next barrier)
        if (it < 63) writeV(cur ^ 1);
    }

    // epilogue: O^T partial (c-major) + stats
    const size_t ob = (size_t)(jh * 4 + b) * CIN * NPIX;
    #pragma unroll
    for (int ct = 0; ct < 8; ++ct)
        #pragma unroll
        for (int r = 0; r < 16; ++r) {
            const int c = ch * 256 + ct * 32 + (r & 3) + 8 * (r >> 2) + 4 * g;
            opart[ob + (size_t)c * NPIX + i_row] = (_Float16)oacc[ct][r];
        }
    if (ch == 0 && g == 0) {
        const size_t idx = ((size_t)(jh * 4 + b) * NPIX + i_row) * 2;
        stats[idx]     = m_run;
        stats[idx + 1] = l_run;
    }
}

// ---------------------------------------------------------------------------
// Combine j-half partials (both c-major): no transpose needed.
// ---------------------------------------------------------------------------
__global__ __launch_bounds__(256) void combine_kernel(
    const _Float16* __restrict__ opart, const float* __restrict__ stats,
    float* __restrict__ out)
{
    const int b  = blockIdx.y;
    const int i0 = blockIdx.x * 64;
    const int t  = threadIdx.x;

    __shared__ float a0s[64], a1s[64];
    if (t < 64) {
        const int i = i0 + t;
        const size_t r0 = ((size_t)b * NPIX + i) * 2;
        const size_t r1 = ((size_t)(4 + b) * NPIX + i) * 2;
        const float m0 = stats[r0], l0 = stats[r0 + 1];
        const float m1 = stats[r1], l1 = stats[r1 + 1];
        const float M  = fmaxf(m0, m1);
        const float w0 = __expf(m0 - M), w1 = __expf(m1 - M);
        const float inv = 1.0f / (l0 * w0 + l1 * w1);
        a0s[t] = w0 * inv;
        a1s[t] = w1 * inv;
    }
    __syncthreads();

    const int ci = t >> 3;
    const int ii = (t & 7) * 8;
    #pragma unroll 4
    for (int pp = 0; pp < 16; ++pp) {
        const int c = pp * 32 + ci;
        const _Float16* p0 = opart + ((size_t)b * CIN + c) * NPIX + i0 + ii;
        const _Float16* p1 = opart + ((size_t)(4 + b) * CIN + c) * NPIX + i0 + ii;
        const f16x8 x0 = *(const f16x8*)p0;
        const f16x8 x1 = *(const f16x8*)p1;
        float* dst = out + ((size_t)b * CIN + c) * NPIX + i0 + ii;
        float4 o0, o1;
        o0.x = a0s[ii + 0] * (float)x0[0] + a1s[ii + 0] * (float)x1[0];
        o0.y = a0s[ii + 1] * (float)x0[1] + a1s[ii + 1] * (float)x1[1];
        o0.z = a0s[ii + 2] * (float)x0[2] + a1s[ii + 2] * (float)x1[2];
        o0.w = a0s[ii + 3] * (float)x0[3] + a1s[ii + 3] * (float)x1[3];
        o1.x = a0s[ii + 4] * (float)x0[4] + a1s[ii + 4] * (float)x1[4];
        o1.y = a0s[ii + 5] * (float)x0[5] + a1s[ii + 5] * (float)x1[5];
        o1.z = a0s[ii + 6] * (float)x0[6] + a1s[ii + 6] * (float)x1[6];
        o1.w = a0s[ii + 7] * (float)x0[7] + a1s[ii + 7] * (float)x1[7];
        *(float4*)dst       = o0;
        *(float4*)(dst + 4) = o1;
    }
}

// ---------------------------------------------------------------------------
extern "C" void kernel_launch(void* const* d_in, const int* in_sizes, int n_in,
                              void* d_out, int out_size, void* d_ws,
                              size_t ws_size, hipStream_t stream)
{
    const float* x   = (const float*)d_in[0];
    const float* f_w = (const float*)d_in[1];
    const float* f_b = (const float*)d_in[2];
    const float* g_w = (const float*)d_in[3];
    const float* g_b = (const float*)d_in[4];
    const float* h_w = (const float*)d_in[5];
    const float* h_b = (const float*)d_in[6];
    float* out = (float*)d_out;

    _Float16* qw = (_Float16*)d_ws;
    _Float16* kw = qw + (size_t)4 * NPIX * 256;
    _Float16* vw = kw + (size_t)4 * NPIX * 256;
    _Float16* op = vw + (size_t)4 * CIN * NPIX;
    float* stats = (float*)(op + (size_t)2 * 4 * CIN * NPIX);

    proj_kernel<<<dim3(64, 16, 4), 256, 0, stream>>>(
        x, f_w, f_b, g_w, g_b, h_w, h_b, qw, kw, vw);
    attn_kernel<<<dim3(256), 512, 0, stream>>>(qw, kw, vw, op, stats);
    combine_kernel<<<dim3(64, 4), 256, 0, stream>>>(op, stats, out);
}